// Round 7
// baseline (199.654 us; speedup 1.0000x reference)
//
#include <hip/hip_runtime.h>
#include <math.h>

#define BB 2
#define LL 2
#define SS 2048
#define DD 512
#define HH 8
#define DHH 64

typedef __attribute__((ext_vector_type(8))) short bf16x8;
typedef __attribute__((ext_vector_type(4))) float f32x4;

#define MFMA16(a, b, c) __builtin_amdgcn_mfma_f32_16x16x32_bf16((a), (b), (c), 0, 0, 0)

#if __has_builtin(__builtin_amdgcn_exp2f)
#define EXP2F(x) __builtin_amdgcn_exp2f(x)
#else
#define EXP2F(x) exp2f(x)
#endif

__device__ __forceinline__ unsigned short f2bf(float f) {
    union { float f; unsigned u; } x; x.f = f;
    unsigned u = x.u;
    return (unsigned short)((u + 0x7fffu + ((u >> 16) & 1u)) >> 16);
}

__device__ __forceinline__ unsigned bcast(float f) {
    union { float f; unsigned u; } x; x.f = f;
    return x.u;
}

// pack 4 fp32 -> 4 bf16 (round-half-up) as ushort4 via v_perm
__device__ __forceinline__ ushort4 pack4(float a, float b, float c, float d) {
    unsigned u0 = bcast(a) + 0x8000u, u1 = bcast(b) + 0x8000u;
    unsigned u2 = bcast(c) + 0x8000u, u3 = bcast(d) + 0x8000u;
    union { uint2 v; ushort4 s; } r;
    r.v.x = __builtin_amdgcn_perm(u1, u0, 0x07060302u);
    r.v.y = __builtin_amdgcn_perm(u3, u2, 0x07060302u);
    return r.s;
}

__device__ __forceinline__ void gload16(const unsigned short* g, unsigned short* l) {
    __builtin_amdgcn_global_load_lds(
        (const __attribute__((address_space(1))) unsigned int*)g,
        (__attribute__((address_space(3))) unsigned int*)l, 16, 0, 0);
}

// ---------------------------------------------------------------
// K0: prep = fp32->bf16 convert (x|Wq|Wk|Wv|Wo) + RoPE table.
// ---------------------------------------------------------------
__global__ __launch_bounds__(256) void prep_kernel(
    const float* __restrict__ x,  const float* __restrict__ wq,
    const float* __restrict__ wk, const float* __restrict__ wv,
    const float* __restrict__ wo, unsigned short* __restrict__ dst,
    float* __restrict__ cos_t, float* __restrict__ sin_t)
{
    int i = blockIdx.x * 256 + threadIdx.x;
    if (i < 1310720) {
        const float* src;
        int local;
        if (i < 1048576)      { src = x;  local = i; }
        else if (i < 1114112) { src = wq; local = i - 1048576; }
        else if (i < 1179648) { src = wk; local = i - 1114112; }
        else if (i < 1245184) { src = wv; local = i - 1179648; }
        else                  { src = wo; local = i - 1245184; }
        float4 v = ((const float4*)src)[local];
        ushort4 o;
        o.x = f2bf(v.x); o.y = f2bf(v.y); o.z = f2bf(v.z); o.w = f2bf(v.w);
        *(ushort4*)&dst[(size_t)i * 4] = o;
    } else {
        int idx = i - 1310720;           // 0..65535
        int s = idx >> 5;
        int f = idx & 31;
        double inv = pow(10000.0, -(double)(2 * f) / (double)DHH);
        double ang = (double)s * inv;
        cos_t[idx] = (float)cos(ang);
        sin_t[idx] = (float)sin(ang);
    }
}

// ---------------------------------------------------------------
// K1: QKV projection, bf16 MFMA. BM=BN=128, BK=32, 4 waves,
// double-buffered LDS via global_load_lds (1 barrier/iter).
// Operand orientation chosen per output so the C-layout's m-dim
// (lane's 4 consecutive regs) is the memory-contiguous dim:
//   mat 0/2 (qm/km, [s][dh]): A=W, B=X -> regs = 4 consecutive dh,
//     RoPE pairs in-lane, ushort4 stores. qm pre-scaled log2e/sqrt(512).
//   mat 1 (vt, [dh][s]):      A=X, B=W -> regs = 4 consecutive s,
//     ushort4 stores.
// ---------------------------------------------------------------
__global__ __launch_bounds__(256) void qkv_mfma_kernel(
    const unsigned short* __restrict__ xb,
    const unsigned short* __restrict__ wqb,
    const unsigned short* __restrict__ wkb,
    const unsigned short* __restrict__ wvb,
    const float* __restrict__ bq, const float* __restrict__ bk,
    const float* __restrict__ bv,
    const float* __restrict__ cos_t, const float* __restrict__ sin_t,
    unsigned short* __restrict__ qm, unsigned short* __restrict__ km,
    unsigned short* __restrict__ vt)
{
    __shared__ __align__(16) unsigned short As[2][4096];   // [row][32]
    __shared__ __align__(16) unsigned short Bs[2][4096];

    const int tid  = threadIdx.x;
    const int w    = tid >> 6;
    const int lane = tid & 63;
    const int c    = lane & 15;
    const int quad = lane >> 4;
    const int mw   = (w & 1) * 64;
    const int nw   = (w >> 1) * 64;

    const int bx    = blockIdx.x;        // 0..11
    const int mat   = bx >> 2;
    const int nloc0 = (bx & 3) * 128;    // feature tile within this matrix
    const int row0  = blockIdx.y * 128;  // x-row tile

    const unsigned short* wsel = (mat == 0) ? wqb : (mat == 1) ? wkb : wvb;
    const float* bsel          = (mat == 0) ? bq  : (mat == 1) ? bk  : bv;

    // mat 0/2: A=W (m=features), B=X (n=x-rows). mat 1: A=X, B=W.
    const unsigned short* aSrc = (mat == 1) ? (xb   + (size_t)row0  * DD)
                                            : (wsel + (size_t)nloc0 * DD);
    const unsigned short* bSrc = (mat == 1) ? (wsel + (size_t)nloc0 * DD)
                                            : (xb   + (size_t)row0  * DD);

    auto stage = [&](int k0, int bb) {
        #pragma unroll
        for (int it = 0; it < 2; ++it) {
            int L   = it * 256 + tid;        // 0..511 chunks of 8
            int row = L >> 2;
            int k8  = (L & 3) * 8;
            gload16(aSrc + (size_t)row * DD + k0 + k8, &As[bb][L * 8]);
            gload16(bSrc + (size_t)row * DD + k0 + k8, &Bs[bb][L * 8]);
        }
    };

    f32x4 acc[4][4];
    #pragma unroll
    for (int i = 0; i < 4; ++i)
        #pragma unroll
        for (int j = 0; j < 4; ++j)
            #pragma unroll
            for (int r = 0; r < 4; ++r) acc[i][j][r] = 0.f;

    stage(0, 0);
    __syncthreads();

    for (int k0 = 0; k0 < DD; k0 += 32) {
        const int bb = (k0 >> 5) & 1;
        if (k0 + 32 < DD) stage(k0 + 32, bb ^ 1);   // flies during compute

        bf16x8 af[4], bfr[4];
        #pragma unroll
        for (int mt = 0; mt < 4; ++mt)
            af[mt] = *(const bf16x8*)&As[bb][(mw + mt * 16 + c) * 32 + quad * 8];
        #pragma unroll
        for (int nt = 0; nt < 4; ++nt)
            bfr[nt] = *(const bf16x8*)&Bs[bb][(nw + nt * 16 + c) * 32 + quad * 8];
        #pragma unroll
        for (int mt = 0; mt < 4; ++mt)
            #pragma unroll
            for (int nt = 0; nt < 4; ++nt)
                acc[mt][nt] = MFMA16(af[mt], bfr[nt], acc[mt][nt]);

        __syncthreads();   // vmcnt(0) drain: next buffer staged
    }

    if (mat == 1) {
        // m = x-row (s), n = feature. Regs = 4 consecutive s at fixed dh.
        #pragma unroll
        for (int nt = 0; nt < 4; ++nt) {
            int col = nloc0 + nw + nt * 16 + c;
            int h = col >> 6, dh = col & 63;
            float bias = bsel[col];
            #pragma unroll
            for (int mt = 0; mt < 4; ++mt) {
                int xr0 = row0 + mw + mt * 16 + quad * 4;
                int bl = xr0 >> 11, s0 = xr0 & 2047;
                ushort4 o = pack4(acc[mt][nt][0] + bias, acc[mt][nt][1] + bias,
                                  acc[mt][nt][2] + bias, acc[mt][nt][3] + bias);
                *(ushort4*)&vt[((size_t)(bl * HH + h) * DHH + dh) * SS + s0] = o;
            }
        }
    } else {
        unsigned short* dst = (mat == 0) ? qm : km;
        // log2(e)/sqrt(512) for Q (exp2-domain softmax), 1.0 for K
        const float qscale = (mat == 0) ? 0.06375871448932861f : 1.0f;
        // m = feature (dh), n = x-row (s). Regs = 4 consecutive dh.
        #pragma unroll
        for (int mt = 0; mt < 4; ++mt) {
            int col0 = nloc0 + mw + mt * 16 + quad * 4;   // 4-aligned
            int h = col0 >> 6, dh0 = col0 & 63;
            int f0 = dh0 >> 1;                            // even
            float4 bias4 = *(const float4*)&bsel[col0];
            #pragma unroll
            for (int nt = 0; nt < 4; ++nt) {
                int xr = row0 + nw + nt * 16 + c;
                int bl = xr >> 11, s = xr & 2047;
                float2 cs = *(const float2*)&cos_t[s * 32 + f0];
                float2 sn = *(const float2*)&sin_t[s * 32 + f0];
                float c0 = cs.x * qscale, s0v = sn.x * qscale;
                float c1 = cs.y * qscale, s1v = sn.y * qscale;
                float v0 = acc[mt][nt][0] + bias4.x;
                float v1 = acc[mt][nt][1] + bias4.y;
                float v2 = acc[mt][nt][2] + bias4.z;
                float v3 = acc[mt][nt][3] + bias4.w;
                ushort4 o = pack4(v0 * c0 - v1 * s0v, v1 * c0 + v0 * s0v,
                                  v2 * c1 - v3 * s1v, v3 * c1 + v2 * s1v);
                *(ushort4*)&dst[((size_t)(bl * HH + h) * SS + s) * DHH + dh0] = o;
            }
        }
    }
}

// ---------------------------------------------------------------
// K2: causal flash attention, bf16 MFMA (round-5 structure).
// Br=128 (4 waves x 32 q), Bc=64. Double-buffered K/V via async
// global_load_lds (XOR-swizzled), one barrier per tile.
// S^T = K Q^T -> packed exp2 -> b64 LDS; O^T = V^T P^T;
// l via ones-row MFMA; no max-subtraction (scores bounded).
// ---------------------------------------------------------------
#define S_P 72

__global__ __launch_bounds__(256, 2) void attn_mfma_kernel(
    const unsigned short* __restrict__ qm,
    const unsigned short* __restrict__ km,
    const unsigned short* __restrict__ vt,
    unsigned short* __restrict__ inter)
{
    __shared__ __align__(16) unsigned short Ks[2][4096];   // [key][dh], swizzled
    __shared__ __align__(16) unsigned short Vs[2][4096];   // [dh][key], swizzled
    __shared__ __align__(16) unsigned short Ps[128 * S_P]; // [q_local][key]

    const int tid  = threadIdx.x;
    const int w    = tid >> 6;
    const int lane = tid & 63;
    const int c    = lane & 15;
    const int quad = lane >> 4;

    const int h  = blockIdx.x;
    const int qt = 15 - blockIdx.y;      // heavy q-tiles dispatched first
    const int bl = blockIdx.z;
    const int qw = qt * 128 + w * 32;

    const size_t seq_base = (size_t)(bl * HH + h) * SS * DHH;  // qm, km
    const size_t vt_base  = (size_t)(bl * HH + h) * DHH * SS;  // vt [dh][s]

    bf16x8 qf[2][2];
    #pragma unroll
    for (int nt = 0; nt < 2; ++nt)
        #pragma unroll
        for (int kk = 0; kk < 2; ++kk)
            qf[nt][kk] = *(const bf16x8*)(qm + seq_base +
                (size_t)(qw + nt * 16 + c) * DHH + kk * 32 + quad * 8);

    f32x4 oacc[4][2];
    f32x4 lacc[2];
    #pragma unroll
    for (int i = 0; i < 4; ++i)
        #pragma unroll
        for (int j = 0; j < 2; ++j)
            #pragma unroll
            for (int r = 0; r < 4; ++r) oacc[i][j][r] = 0.f;
    #pragma unroll
    for (int j = 0; j < 2; ++j)
        #pragma unroll
        for (int r = 0; r < 4; ++r) lacc[j][r] = 0.f;

    bf16x8 ones;
    #pragma unroll
    for (int i = 0; i < 8; ++i) ones[i] = (short)0x3F80;   // bf16 1.0

    const int ntiles = 2 * qt + 2;

    auto stage = [&](int kt, int b) {
        const unsigned short* kg = km + seq_base + (size_t)(kt * 64) * DHH;
        const unsigned short* vg = vt + vt_base + kt * 64;
        #pragma unroll
        for (int it = 0; it < 2; ++it) {
            int L   = it * 256 + tid;        // 0..511
            int row = L >> 3;
            int gch = (L & 7) ^ (row & 7);
            gload16(kg + row * DHH + gch * 8, &Ks[b][L * 8]);
            gload16(vg + (size_t)row * SS + gch * 8, &Vs[b][L * 8]);
        }
    };

    stage(0, 0);
    __syncthreads();

    for (int kt = 0; kt < ntiles; ++kt) {
        const int b = kt & 1;
        const int ktn = (kt + 1 < ntiles) ? kt + 1 : kt;
        stage(ktn, b ^ 1);   // flies during compute below

        if (64 * kt <= qw + 31) {
            f32x4 sacc[4][2];
            #pragma unroll
            for (int mt = 0; mt < 4; ++mt)
                #pragma unroll
                for (int nt = 0; nt < 2; ++nt)
                    #pragma unroll
                    for (int r = 0; r < 4; ++r) sacc[mt][nt][r] = 0.f;
            #pragma unroll
            for (int kk = 0; kk < 2; ++kk) {
                bf16x8 kf[4];
                #pragma unroll
                for (int mt = 0; mt < 4; ++mt) {
                    int rr = mt * 16 + c;
                    kf[mt] = *(const bf16x8*)&Ks[b][rr * 64 +
                        (((kk * 4 + quad) ^ (rr & 7)) * 8)];
                }
                #pragma unroll
                for (int mt = 0; mt < 4; ++mt)
                    #pragma unroll
                    for (int nt = 0; nt < 2; ++nt)
                        sacc[mt][nt] = MFMA16(kf[mt], qf[nt][kk], sacc[mt][nt]);
            }

            const bool need_mask = (64 * kt + 63 > qw);
            #pragma unroll
            for (int mt = 0; mt < 4; ++mt) {
                #pragma unroll
                for (int nt = 0; nt < 2; ++nt) {
                    int q = qw + nt * 16 + c;
                    unsigned u[4];
                    #pragma unroll
                    for (int r = 0; r < 4; ++r) {
                        float p = EXP2F(sacc[mt][nt][r]);
                        if (need_mask) {
                            int key = kt * 64 + mt * 16 + quad * 4 + r;
                            if (key > q) p = 0.f;
                        }
                        u[r] = bcast(p) + 0x8000u;   // round-half-up to bf16
                    }
                    uint2 d;
                    d.x = __builtin_amdgcn_perm(u[1], u[0], 0x07060302u);
                    d.y = __builtin_amdgcn_perm(u[3], u[2], 0x07060302u);
                    *(uint2*)&Ps[(w * 32 + nt * 16 + c) * S_P + mt * 16 + quad * 4] = d;
                }
            }

            #pragma unroll
            for (int kk = 0; kk < 2; ++kk) {
                bf16x8 bp[2];
                #pragma unroll
                for (int nt = 0; nt < 2; ++nt) {
                    bp[nt] = *(const bf16x8*)&Ps[(w * 32 + nt * 16 + c) * S_P +
                                                 kk * 32 + quad * 8];
                    lacc[nt] = MFMA16(ones, bp[nt], lacc[nt]);
                }
                #pragma unroll
                for (int mt4 = 0; mt4 < 4; ++mt4) {
                    int rv = mt4 * 16 + c;
                    bf16x8 av = *(const bf16x8*)&Vs[b][rv * 64 +
                        (((kk * 4 + quad) ^ (rv & 7)) * 8)];
                    oacc[mt4][0] = MFMA16(av, bp[0], oacc[mt4][0]);
                    oacc[mt4][1] = MFMA16(av, bp[1], oacc[mt4][1]);
                }
            }
        }
        __syncthreads();   // vmcnt(0) drain: prefetch ktn complete
    }

    float invl0 = 1.f / lacc[0][0];
    float invl1 = 1.f / lacc[1][0];
    #pragma unroll
    for (int mt4 = 0; mt4 < 4; ++mt4) {
        int dh0 = mt4 * 16 + quad * 4;
        #pragma unroll
        for (int nt = 0; nt < 2; ++nt) {
            int query = qw + nt * 16 + c;
            float il = nt ? invl1 : invl0;
            ushort4 o;
            o.x = f2bf(oacc[mt4][nt][0] * il);
            o.y = f2bf(oacc[mt4][nt][1] * il);
            o.z = f2bf(oacc[mt4][nt][2] * il);
            o.w = f2bf(oacc[mt4][nt][3] * il);
            *(ushort4*)&inter[((size_t)bl * SS + query) * DD + h * DHH + dh0] = o;
        }
    }
}

// ---------------------------------------------------------------
// K3: output projection, bf16 MFMA, swapped orientation (A=Wo,
// B=inter) so lane regs = 4 consecutive out-features -> float4
// stores. Tile 64 features x 128 rows, dbuf, 1 barrier/iter.
// ---------------------------------------------------------------
__global__ __launch_bounds__(256) void outproj_mfma_kernel(
    const unsigned short* __restrict__ ib,
    const unsigned short* __restrict__ wob,
    const float* __restrict__ bo, float* __restrict__ out)
{
    __shared__ __align__(16) unsigned short As[2][2048];   //  64 wo-rows x 32
    __shared__ __align__(16) unsigned short Bs[2][4096];   // 128 x-rows  x 32

    const int tid  = threadIdx.x;
    const int w    = tid >> 6;
    const int lane = tid & 63;
    const int c    = lane & 15;
    const int quad = lane >> 4;
    const int mw   = (w & 1) * 32;    // feature half
    const int nw   = (w >> 1) * 64;   // row half

    const int n0   = blockIdx.x * 64;    // feature tile
    const int row0 = blockIdx.y * 128;   // row tile

    const unsigned short* aSrc = wob + (size_t)n0   * DD;
    const unsigned short* bSrc = ib  + (size_t)row0 * DD;

    auto stage = [&](int k0, int bb) {
        int L = tid;                          // 0..255 -> 64 rows
        gload16(aSrc + (size_t)(L >> 2) * DD + k0 + (L & 3) * 8,
                &As[bb][L * 8]);
        #pragma unroll
        for (int it = 0; it < 2; ++it) {
            int L2 = it * 256 + tid;          // 0..511 -> 128 rows
            gload16(bSrc + (size_t)(L2 >> 2) * DD + k0 + (L2 & 3) * 8,
                    &Bs[bb][L2 * 8]);
        }
    };

    f32x4 acc[2][4];
    #pragma unroll
    for (int i = 0; i < 2; ++i)
        #pragma unroll
        for (int j = 0; j < 4; ++j)
            #pragma unroll
            for (int r = 0; r < 4; ++r) acc[i][j][r] = 0.f;

    stage(0, 0);
    __syncthreads();

    for (int k0 = 0; k0 < DD; k0 += 32) {
        const int bb = (k0 >> 5) & 1;
        if (k0 + 32 < DD) stage(k0 + 32, bb ^ 1);

        bf16x8 af[2], bfr[4];
        #pragma unroll
        for (int mt = 0; mt < 2; ++mt)
            af[mt] = *(const bf16x8*)&As[bb][(mw + mt * 16 + c) * 32 + quad * 8];
        #pragma unroll
        for (int nt = 0; nt < 4; ++nt)
            bfr[nt] = *(const bf16x8*)&Bs[bb][(nw + nt * 16 + c) * 32 + quad * 8];
        #pragma unroll
        for (int mt = 0; mt < 2; ++mt)
            #pragma unroll
            for (int nt = 0; nt < 4; ++nt)
                acc[mt][nt] = MFMA16(af[mt], bfr[nt], acc[mt][nt]);

        __syncthreads();
    }

    #pragma unroll
    for (int mt = 0; mt < 2; ++mt) {
        int col0 = n0 + mw + mt * 16 + quad * 4;   // 4-aligned
        float4 b4 = *(const float4*)&bo[col0];
        #pragma unroll
        for (int nt = 0; nt < 4; ++nt) {
            int xr = row0 + nw + nt * 16 + c;
            float4 o;
            o.x = acc[mt][nt][0] + b4.x;
            o.y = acc[mt][nt][1] + b4.y;
            o.z = acc[mt][nt][2] + b4.z;
            o.w = acc[mt][nt][3] + b4.w;
            *(float4*)&out[(size_t)xr * DD + col0] = o;
        }
    }
}

// ---------------------------------------------------------------
extern "C" void kernel_launch(void* const* d_in, const int* in_sizes, int n_in,
                              void* d_out, int out_size, void* d_ws, size_t ws_size,
                              hipStream_t stream)
{
    const float* x  = (const float*)d_in[0];
    const float* Wq = (const float*)d_in[1];
    const float* bq = (const float*)d_in[2];
    const float* Wk = (const float*)d_in[3];
    const float* bk = (const float*)d_in[4];
    const float* Wv = (const float*)d_in[5];
    const float* bv = (const float*)d_in[6];
    const float* Wo = (const float*)d_in[7];
    const float* bo = (const float*)d_in[8];
    float* out = (float*)d_out;
    char* ws = (char*)d_ws;

    // Workspace layout (bytes):
    unsigned short* inter = (unsigned short*)(ws);             //  8,388,608
    float* cos_t = (float*)(ws + 8388608);                     //    262,144
    float* sin_t = (float*)(ws + 8650752);                     //    262,144
    unsigned short* xb  = (unsigned short*)(ws + 8912896);     //  8,388,608
    unsigned short* wqb = (unsigned short*)(ws + 17301504);    //    524,288
    unsigned short* wkb = (unsigned short*)(ws + 17825792);    //    524,288
    unsigned short* wvb = (unsigned short*)(ws + 18350080);    //    524,288
    unsigned short* wob = (unsigned short*)(ws + 18874368);    //    524,288
    unsigned short* qm  = (unsigned short*)(ws + 19398656);    //  8,388,608
    unsigned short* km  = (unsigned short*)(ws + 27787264);    //  8,388,608
    unsigned short* vt  = (unsigned short*)(ws + 36175872);    //  8,388,608
    // total 44,564,480 bytes

    prep_kernel<<<dim3(5376), dim3(256), 0, stream>>>(
        x, Wq, Wk, Wv, Wo, xb, cos_t, sin_t);
    qkv_mfma_kernel<<<dim3(12, 64), dim3(256), 0, stream>>>(
        xb, wqb, wkb, wvb, bq, bk, bv, cos_t, sin_t, qm, km, vt);
    attn_mfma_kernel<<<dim3(HH, 16, BB * LL), dim3(256), 0, stream>>>(qm, km, vt, inter);
    outproj_mfma_kernel<<<dim3(8, 64), dim3(256), 0, stream>>>(inter, wob, bo, out);
}

// Round 8
// 194.602 us; speedup vs baseline: 1.0260x; 1.0260x over previous
//
#include <hip/hip_runtime.h>
#include <math.h>

#define BB 2
#define LL 2
#define SS 2048
#define DD 512
#define HH 8
#define DHH 64

typedef __attribute__((ext_vector_type(8))) short bf16x8;
typedef __attribute__((ext_vector_type(4))) float f32x4;

#define MFMA16(a, b, c) __builtin_amdgcn_mfma_f32_16x16x32_bf16((a), (b), (c), 0, 0, 0)

#if __has_builtin(__builtin_amdgcn_exp2f)
#define EXP2F(x) __builtin_amdgcn_exp2f(x)
#else
#define EXP2F(x) exp2f(x)
#endif

// Wait for all prior-iteration DMA loads (issued a full tile ago -> ~free),
// then sync waves WITHOUT the compiler's forced vmcnt(0) drain of the
// freshly-issued next-tile prefetch. Single asm w/ memory clobber so no
// memory op is scheduled across it.
#define PIPELINE_SYNC() asm volatile("s_waitcnt vmcnt(0)\n\ts_barrier" ::: "memory")

__device__ __forceinline__ unsigned short f2bf(float f) {
    union { float f; unsigned u; } x; x.f = f;
    unsigned u = x.u;
    return (unsigned short)((u + 0x7fffu + ((u >> 16) & 1u)) >> 16);
}

__device__ __forceinline__ unsigned bcast(float f) {
    union { float f; unsigned u; } x; x.f = f;
    return x.u;
}

// pack 4 fp32 -> 4 bf16 (round-half-up) as ushort4 via v_perm
__device__ __forceinline__ ushort4 pack4(float a, float b, float c, float d) {
    unsigned u0 = bcast(a) + 0x8000u, u1 = bcast(b) + 0x8000u;
    unsigned u2 = bcast(c) + 0x8000u, u3 = bcast(d) + 0x8000u;
    union { uint2 v; ushort4 s; } r;
    r.v.x = __builtin_amdgcn_perm(u1, u0, 0x07060302u);
    r.v.y = __builtin_amdgcn_perm(u3, u2, 0x07060302u);
    return r.s;
}

__device__ __forceinline__ void gload16(const unsigned short* g, unsigned short* l) {
    __builtin_amdgcn_global_load_lds(
        (const __attribute__((address_space(1))) unsigned int*)g,
        (__attribute__((address_space(3))) unsigned int*)l, 16, 0, 0);
}

// ---------------------------------------------------------------
// K0: prep = fp32->bf16 convert (x|Wq|Wk|Wv|Wo) + RoPE table.
// ---------------------------------------------------------------
__global__ __launch_bounds__(256) void prep_kernel(
    const float* __restrict__ x,  const float* __restrict__ wq,
    const float* __restrict__ wk, const float* __restrict__ wv,
    const float* __restrict__ wo, unsigned short* __restrict__ dst,
    float* __restrict__ cos_t, float* __restrict__ sin_t)
{
    int i = blockIdx.x * 256 + threadIdx.x;
    if (i < 1310720) {
        const float* src;
        int local;
        if (i < 1048576)      { src = x;  local = i; }
        else if (i < 1114112) { src = wq; local = i - 1048576; }
        else if (i < 1179648) { src = wk; local = i - 1114112; }
        else if (i < 1245184) { src = wv; local = i - 1179648; }
        else                  { src = wo; local = i - 1245184; }
        float4 v = ((const float4*)src)[local];
        ushort4 o;
        o.x = f2bf(v.x); o.y = f2bf(v.y); o.z = f2bf(v.z); o.w = f2bf(v.w);
        *(ushort4*)&dst[(size_t)i * 4] = o;
    } else {
        int idx = i - 1310720;           // 0..65535
        int s = idx >> 5;
        int f = idx & 31;
        double inv = pow(10000.0, -(double)(2 * f) / (double)DHH);
        double ang = (double)s * inv;
        cos_t[idx] = (float)cos(ang);
        sin_t[idx] = (float)sin(ang);
    }
}

// ---------------------------------------------------------------
// K1: QKV projection, bf16 MFMA. BM=BN=128, BK=32, 4 waves,
// double-buffered LDS via global_load_lds; pipelined sync (see
// PIPELINE_SYNC): wait own prior loads, raw barrier, then issue
// next-tile DMA so it overlaps this tile's MFMA.
//   mat 0/2 (qm/km, [s][dh]): A=W, B=X -> regs = 4 consecutive dh,
//     RoPE pairs in-lane, ushort4 stores. qm pre-scaled log2e/sqrt(512).
//   mat 1 (vt, [dh][s]):      A=X, B=W -> regs = 4 consecutive s.
// ---------------------------------------------------------------
__global__ __launch_bounds__(256) void qkv_mfma_kernel(
    const unsigned short* __restrict__ xb,
    const unsigned short* __restrict__ wqb,
    const unsigned short* __restrict__ wkb,
    const unsigned short* __restrict__ wvb,
    const float* __restrict__ bq, const float* __restrict__ bk,
    const float* __restrict__ bv,
    const float* __restrict__ cos_t, const float* __restrict__ sin_t,
    unsigned short* __restrict__ qm, unsigned short* __restrict__ km,
    unsigned short* __restrict__ vt)
{
    __shared__ __align__(16) unsigned short As[2][4096];   // [row][32]
    __shared__ __align__(16) unsigned short Bs[2][4096];

    const int tid  = threadIdx.x;
    const int w    = tid >> 6;
    const int lane = tid & 63;
    const int c    = lane & 15;
    const int quad = lane >> 4;
    const int mw   = (w & 1) * 64;
    const int nw   = (w >> 1) * 64;

    const int bx    = blockIdx.x;        // 0..11
    const int mat   = bx >> 2;
    const int nloc0 = (bx & 3) * 128;    // feature tile within this matrix
    const int row0  = blockIdx.y * 128;  // x-row tile

    const unsigned short* wsel = (mat == 0) ? wqb : (mat == 1) ? wkb : wvb;
    const float* bsel          = (mat == 0) ? bq  : (mat == 1) ? bk  : bv;

    // mat 0/2: A=W (m=features), B=X (n=x-rows). mat 1: A=X, B=W.
    const unsigned short* aSrc = (mat == 1) ? (xb   + (size_t)row0  * DD)
                                            : (wsel + (size_t)nloc0 * DD);
    const unsigned short* bSrc = (mat == 1) ? (wsel + (size_t)nloc0 * DD)
                                            : (xb   + (size_t)row0  * DD);

    auto stage = [&](int k0, int bb) {
        #pragma unroll
        for (int it = 0; it < 2; ++it) {
            int L   = it * 256 + tid;        // 0..511 chunks of 8
            int row = L >> 2;
            int k8  = (L & 3) * 8;
            gload16(aSrc + (size_t)row * DD + k0 + k8, &As[bb][L * 8]);
            gload16(bSrc + (size_t)row * DD + k0 + k8, &Bs[bb][L * 8]);
        }
    };

    f32x4 acc[4][4];
    #pragma unroll
    for (int i = 0; i < 4; ++i)
        #pragma unroll
        for (int j = 0; j < 4; ++j)
            #pragma unroll
            for (int r = 0; r < 4; ++r) acc[i][j][r] = 0.f;

    stage(0, 0);

    for (int k0 = 0; k0 < DD; k0 += 32) {
        const int bb = (k0 >> 5) & 1;
        PIPELINE_SYNC();                    // this tile staged; prev compute done
        if (k0 + 32 < DD) stage(k0 + 32, bb ^ 1);   // flies under MFMA below

        bf16x8 af[4], bfr[4];
        #pragma unroll
        for (int mt = 0; mt < 4; ++mt)
            af[mt] = *(const bf16x8*)&As[bb][(mw + mt * 16 + c) * 32 + quad * 8];
        #pragma unroll
        for (int nt = 0; nt < 4; ++nt)
            bfr[nt] = *(const bf16x8*)&Bs[bb][(nw + nt * 16 + c) * 32 + quad * 8];
        #pragma unroll
        for (int mt = 0; mt < 4; ++mt)
            #pragma unroll
            for (int nt = 0; nt < 4; ++nt)
                acc[mt][nt] = MFMA16(af[mt], bfr[nt], acc[mt][nt]);
    }

    if (mat == 1) {
        // m = x-row (s), n = feature. Regs = 4 consecutive s at fixed dh.
        #pragma unroll
        for (int nt = 0; nt < 4; ++nt) {
            int col = nloc0 + nw + nt * 16 + c;
            int h = col >> 6, dh = col & 63;
            float bias = bsel[col];
            #pragma unroll
            for (int mt = 0; mt < 4; ++mt) {
                int xr0 = row0 + mw + mt * 16 + quad * 4;
                int bl = xr0 >> 11, s0 = xr0 & 2047;
                ushort4 o = pack4(acc[mt][nt][0] + bias, acc[mt][nt][1] + bias,
                                  acc[mt][nt][2] + bias, acc[mt][nt][3] + bias);
                *(ushort4*)&vt[((size_t)(bl * HH + h) * DHH + dh) * SS + s0] = o;
            }
        }
    } else {
        unsigned short* dst = (mat == 0) ? qm : km;
        // log2(e)/sqrt(512) for Q (exp2-domain softmax), 1.0 for K
        const float qscale = (mat == 0) ? 0.06375871448932861f : 1.0f;
        // m = feature (dh), n = x-row (s). Regs = 4 consecutive dh.
        #pragma unroll
        for (int mt = 0; mt < 4; ++mt) {
            int col0 = nloc0 + mw + mt * 16 + quad * 4;   // 4-aligned
            int h = col0 >> 6, dh0 = col0 & 63;
            int f0 = dh0 >> 1;                            // even
            float4 bias4 = *(const float4*)&bsel[col0];
            #pragma unroll
            for (int nt = 0; nt < 4; ++nt) {
                int xr = row0 + nw + nt * 16 + c;
                int bl = xr >> 11, s = xr & 2047;
                float2 cs = *(const float2*)&cos_t[s * 32 + f0];
                float2 sn = *(const float2*)&sin_t[s * 32 + f0];
                float c0 = cs.x * qscale, s0v = sn.x * qscale;
                float c1 = cs.y * qscale, s1v = sn.y * qscale;
                float v0 = acc[mt][nt][0] + bias4.x;
                float v1 = acc[mt][nt][1] + bias4.y;
                float v2 = acc[mt][nt][2] + bias4.z;
                float v3 = acc[mt][nt][3] + bias4.w;
                ushort4 o = pack4(v0 * c0 - v1 * s0v, v1 * c0 + v0 * s0v,
                                  v2 * c1 - v3 * s1v, v3 * c1 + v2 * s1v);
                *(ushort4*)&dst[((size_t)(bl * HH + h) * SS + s) * DHH + dh0] = o;
            }
        }
    }
}

// ---------------------------------------------------------------
// K2: causal flash attention, bf16 MFMA.
// Br=128 (4 waves x 32 q), Bc=64. Double-buffered K/V via async
// global_load_lds (XOR-swizzled), pipelined sync per tile (see
// PIPELINE_SYNC — next-tile DMA overlaps this tile's compute).
// S^T = K Q^T -> packed exp2 -> b64 LDS; O^T = V^T P^T;
// l via ones-row MFMA; no max-subtraction (scores bounded).
// ---------------------------------------------------------------
#define S_P 72

__global__ __launch_bounds__(256, 2) void attn_mfma_kernel(
    const unsigned short* __restrict__ qm,
    const unsigned short* __restrict__ km,
    const unsigned short* __restrict__ vt,
    unsigned short* __restrict__ inter)
{
    __shared__ __align__(16) unsigned short Ks[2][4096];   // [key][dh], swizzled
    __shared__ __align__(16) unsigned short Vs[2][4096];   // [dh][key], swizzled
    __shared__ __align__(16) unsigned short Ps[128 * S_P]; // [q_local][key]

    const int tid  = threadIdx.x;
    const int w    = tid >> 6;
    const int lane = tid & 63;
    const int c    = lane & 15;
    const int quad = lane >> 4;

    const int h  = blockIdx.x;
    const int qt = 15 - blockIdx.y;      // heavy q-tiles dispatched first
    const int bl = blockIdx.z;
    const int qw = qt * 128 + w * 32;

    const size_t seq_base = (size_t)(bl * HH + h) * SS * DHH;  // qm, km
    const size_t vt_base  = (size_t)(bl * HH + h) * DHH * SS;  // vt [dh][s]

    bf16x8 qf[2][2];
    #pragma unroll
    for (int nt = 0; nt < 2; ++nt)
        #pragma unroll
        for (int kk = 0; kk < 2; ++kk)
            qf[nt][kk] = *(const bf16x8*)(qm + seq_base +
                (size_t)(qw + nt * 16 + c) * DHH + kk * 32 + quad * 8);

    f32x4 oacc[4][2];
    f32x4 lacc[2];
    #pragma unroll
    for (int i = 0; i < 4; ++i)
        #pragma unroll
        for (int j = 0; j < 2; ++j)
            #pragma unroll
            for (int r = 0; r < 4; ++r) oacc[i][j][r] = 0.f;
    #pragma unroll
    for (int j = 0; j < 2; ++j)
        #pragma unroll
        for (int r = 0; r < 4; ++r) lacc[j][r] = 0.f;

    bf16x8 ones;
    #pragma unroll
    for (int i = 0; i < 8; ++i) ones[i] = (short)0x3F80;   // bf16 1.0

    const int ntiles = 2 * qt + 2;

    auto stage = [&](int kt, int b) {
        const unsigned short* kg = km + seq_base + (size_t)(kt * 64) * DHH;
        const unsigned short* vg = vt + vt_base + kt * 64;
        #pragma unroll
        for (int it = 0; it < 2; ++it) {
            int L   = it * 256 + tid;        // 0..511
            int row = L >> 3;
            int gch = (L & 7) ^ (row & 7);
            gload16(kg + row * DHH + gch * 8, &Ks[b][L * 8]);
            gload16(vg + (size_t)row * SS + gch * 8, &Vs[b][L * 8]);
        }
    };

    stage(0, 0);

    for (int kt = 0; kt < ntiles; ++kt) {
        const int b = kt & 1;
        PIPELINE_SYNC();                   // tile kt staged; kt-1 compute done
        if (kt + 1 < ntiles) stage(kt + 1, b ^ 1);   // flies under compute

        if (64 * kt <= qw + 31) {
            f32x4 sacc[4][2];
            #pragma unroll
            for (int mt = 0; mt < 4; ++mt)
                #pragma unroll
                for (int nt = 0; nt < 2; ++nt)
                    #pragma unroll
                    for (int r = 0; r < 4; ++r) sacc[mt][nt][r] = 0.f;
            #pragma unroll
            for (int kk = 0; kk < 2; ++kk) {
                bf16x8 kf[4];
                #pragma unroll
                for (int mt = 0; mt < 4; ++mt) {
                    int rr = mt * 16 + c;
                    kf[mt] = *(const bf16x8*)&Ks[b][rr * 64 +
                        (((kk * 4 + quad) ^ (rr & 7)) * 8)];
                }
                #pragma unroll
                for (int mt = 0; mt < 4; ++mt)
                    #pragma unroll
                    for (int nt = 0; nt < 2; ++nt)
                        sacc[mt][nt] = MFMA16(kf[mt], qf[nt][kk], sacc[mt][nt]);
            }

            const bool need_mask = (64 * kt + 63 > qw);
            #pragma unroll
            for (int mt = 0; mt < 4; ++mt) {
                #pragma unroll
                for (int nt = 0; nt < 2; ++nt) {
                    int q = qw + nt * 16 + c;
                    unsigned u[4];
                    #pragma unroll
                    for (int r = 0; r < 4; ++r) {
                        float p = EXP2F(sacc[mt][nt][r]);
                        if (need_mask) {
                            int key = kt * 64 + mt * 16 + quad * 4 + r;
                            if (key > q) p = 0.f;
                        }
                        u[r] = bcast(p) + 0x8000u;   // round-half-up to bf16
                    }
                    uint2 d;
                    d.x = __builtin_amdgcn_perm(u[1], u[0], 0x07060302u);
                    d.y = __builtin_amdgcn_perm(u[3], u[2], 0x07060302u);
                    *(uint2*)&Ps[(w * 32 + nt * 16 + c) * S_P + mt * 16 + quad * 4] = d;
                }
            }

            #pragma unroll
            for (int kk = 0; kk < 2; ++kk) {
                bf16x8 bp[2];
                #pragma unroll
                for (int nt = 0; nt < 2; ++nt) {
                    bp[nt] = *(const bf16x8*)&Ps[(w * 32 + nt * 16 + c) * S_P +
                                                 kk * 32 + quad * 8];
                    lacc[nt] = MFMA16(ones, bp[nt], lacc[nt]);
                }
                #pragma unroll
                for (int mt4 = 0; mt4 < 4; ++mt4) {
                    int rv = mt4 * 16 + c;
                    bf16x8 av = *(const bf16x8*)&Vs[b][rv * 64 +
                        (((kk * 4 + quad) ^ (rv & 7)) * 8)];
                    oacc[mt4][0] = MFMA16(av, bp[0], oacc[mt4][0]);
                    oacc[mt4][1] = MFMA16(av, bp[1], oacc[mt4][1]);
                }
            }
        }
    }

    float invl0 = 1.f / lacc[0][0];
    float invl1 = 1.f / lacc[1][0];
    #pragma unroll
    for (int mt4 = 0; mt4 < 4; ++mt4) {
        int dh0 = mt4 * 16 + quad * 4;
        #pragma unroll
        for (int nt = 0; nt < 2; ++nt) {
            int query = qw + nt * 16 + c;
            float il = nt ? invl1 : invl0;
            ushort4 o;
            o.x = f2bf(oacc[mt4][nt][0] * il);
            o.y = f2bf(oacc[mt4][nt][1] * il);
            o.z = f2bf(oacc[mt4][nt][2] * il);
            o.w = f2bf(oacc[mt4][nt][3] * il);
            *(ushort4*)&inter[((size_t)bl * SS + query) * DD + h * DHH + dh0] = o;
        }
    }
}

// ---------------------------------------------------------------
// K3: output projection, bf16 MFMA, swapped orientation (A=Wo,
// B=inter) so lane regs = 4 consecutive out-features -> float4
// stores. Tile 64 features x 128 rows, dbuf, pipelined sync.
// ---------------------------------------------------------------
__global__ __launch_bounds__(256) void outproj_mfma_kernel(
    const unsigned short* __restrict__ ib,
    const unsigned short* __restrict__ wob,
    const float* __restrict__ bo, float* __restrict__ out)
{
    __shared__ __align__(16) unsigned short As[2][2048];   //  64 wo-rows x 32
    __shared__ __align__(16) unsigned short Bs[2][4096];   // 128 x-rows  x 32

    const int tid  = threadIdx.x;
    const int w    = tid >> 6;
    const int lane = tid & 63;
    const int c    = lane & 15;
    const int quad = lane >> 4;
    const int mw   = (w & 1) * 32;    // feature half
    const int nw   = (w >> 1) * 64;   // row half

    const int n0   = blockIdx.x * 64;    // feature tile
    const int row0 = blockIdx.y * 128;   // row tile

    const unsigned short* aSrc = wob + (size_t)n0   * DD;
    const unsigned short* bSrc = ib  + (size_t)row0 * DD;

    auto stage = [&](int k0, int bb) {
        int L = tid;                          // 0..255 -> 64 rows
        gload16(aSrc + (size_t)(L >> 2) * DD + k0 + (L & 3) * 8,
                &As[bb][L * 8]);
        #pragma unroll
        for (int it = 0; it < 2; ++it) {
            int L2 = it * 256 + tid;          // 0..511 -> 128 rows
            gload16(bSrc + (size_t)(L2 >> 2) * DD + k0 + (L2 & 3) * 8,
                    &Bs[bb][L2 * 8]);
        }
    };

    f32x4 acc[2][4];
    #pragma unroll
    for (int i = 0; i < 2; ++i)
        #pragma unroll
        for (int j = 0; j < 4; ++j)
            #pragma unroll
            for (int r = 0; r < 4; ++r) acc[i][j][r] = 0.f;

    stage(0, 0);

    for (int k0 = 0; k0 < DD; k0 += 32) {
        const int bb = (k0 >> 5) & 1;
        PIPELINE_SYNC();
        if (k0 + 32 < DD) stage(k0 + 32, bb ^ 1);

        bf16x8 af[2], bfr[4];
        #pragma unroll
        for (int mt = 0; mt < 2; ++mt)
            af[mt] = *(const bf16x8*)&As[bb][(mw + mt * 16 + c) * 32 + quad * 8];
        #pragma unroll
        for (int nt = 0; nt < 4; ++nt)
            bfr[nt] = *(const bf16x8*)&Bs[bb][(nw + nt * 16 + c) * 32 + quad * 8];
        #pragma unroll
        for (int mt = 0; mt < 2; ++mt)
            #pragma unroll
            for (int nt = 0; nt < 4; ++nt)
                acc[mt][nt] = MFMA16(af[mt], bfr[nt], acc[mt][nt]);
    }

    #pragma unroll
    for (int mt = 0; mt < 2; ++mt) {
        int col0 = n0 + mw + mt * 16 + quad * 4;   // 4-aligned
        float4 b4 = *(const float4*)&bo[col0];
        #pragma unroll
        for (int nt = 0; nt < 4; ++nt) {
            int xr = row0 + nw + nt * 16 + c;
            float4 o;
            o.x = acc[mt][nt][0] + b4.x;
            o.y = acc[mt][nt][1] + b4.y;
            o.z = acc[mt][nt][2] + b4.z;
            o.w = acc[mt][nt][3] + b4.w;
            *(float4*)&out[(size_t)xr * DD + col0] = o;
        }
    }
}

// ---------------------------------------------------------------
extern "C" void kernel_launch(void* const* d_in, const int* in_sizes, int n_in,
                              void* d_out, int out_size, void* d_ws, size_t ws_size,
                              hipStream_t stream)
{
    const float* x  = (const float*)d_in[0];
    const float* Wq = (const float*)d_in[1];
    const float* bq = (const float*)d_in[2];
    const float* Wk = (const float*)d_in[3];
    const float* bk = (const float*)d_in[4];
    const float* Wv = (const float*)d_in[5];
    const float* bv = (const float*)d_in[6];
    const float* Wo = (const float*)d_in[7];
    const float* bo = (const float*)d_in[8];
    float* out = (float*)d_out;
    char* ws = (char*)d_ws;

    // Workspace layout (bytes):
    unsigned short* inter = (unsigned short*)(ws);             //  8,388,608
    float* cos_t = (float*)(ws + 8388608);                     //    262,144
    float* sin_t = (float*)(ws + 8650752);                     //    262,144
    unsigned short* xb  = (unsigned short*)(ws + 8912896);     //  8,388,608
    unsigned short* wqb = (unsigned short*)(ws + 17301504);    //    524,288
    unsigned short* wkb = (unsigned short*)(ws + 17825792);    //    524,288
    unsigned short* wvb = (unsigned short*)(ws + 18350080);    //    524,288
    unsigned short* wob = (unsigned short*)(ws + 18874368);    //    524,288
    unsigned short* qm  = (unsigned short*)(ws + 19398656);    //  8,388,608
    unsigned short* km  = (unsigned short*)(ws + 27787264);    //  8,388,608
    unsigned short* vt  = (unsigned short*)(ws + 36175872);    //  8,388,608
    // total 44,564,480 bytes

    prep_kernel<<<dim3(5376), dim3(256), 0, stream>>>(
        x, Wq, Wk, Wv, Wo, xb, cos_t, sin_t);
    qkv_mfma_kernel<<<dim3(12, 64), dim3(256), 0, stream>>>(
        xb, wqb, wkb, wvb, bq, bk, bv, cos_t, sin_t, qm, km, vt);
    attn_mfma_kernel<<<dim3(HH, 16, BB * LL), dim3(256), 0, stream>>>(qm, km, vt, inter);
    outproj_mfma_kernel<<<dim3(8, 64), dim3(256), 0, stream>>>(inter, wob, bo, out);
}

// Round 9
// 177.901 us; speedup vs baseline: 1.1223x; 1.0939x over previous
//
#include <hip/hip_runtime.h>
#include <math.h>

#define BB 2
#define LL 2
#define SS 2048
#define DD 512
#define HH 8
#define DHH 64

typedef __attribute__((ext_vector_type(8))) short bf16x8;
typedef __attribute__((ext_vector_type(4))) float f32x4;

#define MFMA16(a, b, c) __builtin_amdgcn_mfma_f32_16x16x32_bf16((a), (b), (c), 0, 0, 0)

#if __has_builtin(__builtin_amdgcn_exp2f)
#define EXP2F(x) __builtin_amdgcn_exp2f(x)
#else
#define EXP2F(x) exp2f(x)
#endif

// Wait own prior-iteration DMA loads, then raw barrier (no forced drain of
// the just-issued next-tile prefetch). Safe only when cross-wave LDS data
// was produced by global_load_lds (vmcnt-tracked); cross-wave ds_write data
// needs a real __syncthreads().
#define PIPELINE_SYNC() asm volatile("s_waitcnt vmcnt(0)\n\ts_barrier" ::: "memory")

__device__ __forceinline__ unsigned short f2bf(float f) {
    union { float f; unsigned u; } x; x.f = f;
    unsigned u = x.u;
    return (unsigned short)((u + 0x7fffu + ((u >> 16) & 1u)) >> 16);
}

__device__ __forceinline__ unsigned bcast(float f) {
    union { float f; unsigned u; } x; x.f = f;
    return x.u;
}

// pack 4 fp32 -> 4 bf16 (round-half-up) as ushort4 via v_perm
__device__ __forceinline__ ushort4 pack4(float a, float b, float c, float d) {
    unsigned u0 = bcast(a) + 0x8000u, u1 = bcast(b) + 0x8000u;
    unsigned u2 = bcast(c) + 0x8000u, u3 = bcast(d) + 0x8000u;
    union { uint2 v; ushort4 s; } r;
    r.v.x = __builtin_amdgcn_perm(u1, u0, 0x07060302u);
    r.v.y = __builtin_amdgcn_perm(u3, u2, 0x07060302u);
    return r.s;
}

__device__ __forceinline__ void gload16(const unsigned short* g, unsigned short* l) {
    __builtin_amdgcn_global_load_lds(
        (const __attribute__((address_space(1))) unsigned int*)g,
        (__attribute__((address_space(3))) unsigned int*)l, 16, 0, 0);
}

// ---------------------------------------------------------------
// K0: prep = fp32->bf16 convert (x|Wq|Wk|Wv|Wo) + RoPE table.
// ---------------------------------------------------------------
__global__ __launch_bounds__(256) void prep_kernel(
    const float* __restrict__ x,  const float* __restrict__ wq,
    const float* __restrict__ wk, const float* __restrict__ wv,
    const float* __restrict__ wo, unsigned short* __restrict__ dst,
    float* __restrict__ cos_t, float* __restrict__ sin_t)
{
    int i = blockIdx.x * 256 + threadIdx.x;
    if (i < 1310720) {
        const float* src;
        int local;
        if (i < 1048576)      { src = x;  local = i; }
        else if (i < 1114112) { src = wq; local = i - 1048576; }
        else if (i < 1179648) { src = wk; local = i - 1114112; }
        else if (i < 1245184) { src = wv; local = i - 1179648; }
        else                  { src = wo; local = i - 1245184; }
        float4 v = ((const float4*)src)[local];
        ushort4 o;
        o.x = f2bf(v.x); o.y = f2bf(v.y); o.z = f2bf(v.z); o.w = f2bf(v.w);
        *(ushort4*)&dst[(size_t)i * 4] = o;
    } else {
        int idx = i - 1310720;           // 0..65535
        int s = idx >> 5;
        int f = idx & 31;
        double inv = pow(10000.0, -(double)(2 * f) / (double)DHH);
        double ang = (double)s * inv;
        cos_t[idx] = (float)cos(ang);
        sin_t[idx] = (float)sin(ang);
    }
}

// ---------------------------------------------------------------
// K1: QKV projection, bf16 MFMA. BM=BN=128, BK=32, 4 waves,
// double-buffered LDS via global_load_lds; pipelined sync.
//   mat 0/2 (qm/km, [s][dh]): A=W, B=X -> regs = 4 consecutive dh,
//     RoPE pairs in-lane, ushort4 stores. qm pre-scaled log2e/sqrt(512).
//   mat 1 (vt, [dh][s]):      A=X, B=W -> regs = 4 consecutive s.
// ---------------------------------------------------------------
__global__ __launch_bounds__(256) void qkv_mfma_kernel(
    const unsigned short* __restrict__ xb,
    const unsigned short* __restrict__ wqb,
    const unsigned short* __restrict__ wkb,
    const unsigned short* __restrict__ wvb,
    const float* __restrict__ bq, const float* __restrict__ bk,
    const float* __restrict__ bv,
    const float* __restrict__ cos_t, const float* __restrict__ sin_t,
    unsigned short* __restrict__ qm, unsigned short* __restrict__ km,
    unsigned short* __restrict__ vt)
{
    __shared__ __align__(16) unsigned short As[2][4096];   // [row][32]
    __shared__ __align__(16) unsigned short Bs[2][4096];

    const int tid  = threadIdx.x;
    const int w    = tid >> 6;
    const int lane = tid & 63;
    const int c    = lane & 15;
    const int quad = lane >> 4;
    const int mw   = (w & 1) * 64;
    const int nw   = (w >> 1) * 64;

    const int bx    = blockIdx.x;        // 0..11
    const int mat   = bx >> 2;
    const int nloc0 = (bx & 3) * 128;    // feature tile within this matrix
    const int row0  = blockIdx.y * 128;  // x-row tile

    const unsigned short* wsel = (mat == 0) ? wqb : (mat == 1) ? wkb : wvb;
    const float* bsel          = (mat == 0) ? bq  : (mat == 1) ? bk  : bv;

    // mat 0/2: A=W (m=features), B=X (n=x-rows). mat 1: A=X, B=W.
    const unsigned short* aSrc = (mat == 1) ? (xb   + (size_t)row0  * DD)
                                            : (wsel + (size_t)nloc0 * DD);
    const unsigned short* bSrc = (mat == 1) ? (wsel + (size_t)nloc0 * DD)
                                            : (xb   + (size_t)row0  * DD);

    auto stage = [&](int k0, int bb) {
        #pragma unroll
        for (int it = 0; it < 2; ++it) {
            int L   = it * 256 + tid;        // 0..511 chunks of 8
            int row = L >> 2;
            int k8  = (L & 3) * 8;
            gload16(aSrc + (size_t)row * DD + k0 + k8, &As[bb][L * 8]);
            gload16(bSrc + (size_t)row * DD + k0 + k8, &Bs[bb][L * 8]);
        }
    };

    f32x4 acc[4][4];
    #pragma unroll
    for (int i = 0; i < 4; ++i)
        #pragma unroll
        for (int j = 0; j < 4; ++j)
            #pragma unroll
            for (int r = 0; r < 4; ++r) acc[i][j][r] = 0.f;

    stage(0, 0);

    for (int k0 = 0; k0 < DD; k0 += 32) {
        const int bb = (k0 >> 5) & 1;
        PIPELINE_SYNC();                    // this tile staged; prev compute done
        if (k0 + 32 < DD) stage(k0 + 32, bb ^ 1);   // flies under MFMA below

        bf16x8 af[4], bfr[4];
        #pragma unroll
        for (int mt = 0; mt < 4; ++mt)
            af[mt] = *(const bf16x8*)&As[bb][(mw + mt * 16 + c) * 32 + quad * 8];
        #pragma unroll
        for (int nt = 0; nt < 4; ++nt)
            bfr[nt] = *(const bf16x8*)&Bs[bb][(nw + nt * 16 + c) * 32 + quad * 8];
        #pragma unroll
        for (int mt = 0; mt < 4; ++mt)
            #pragma unroll
            for (int nt = 0; nt < 4; ++nt)
                acc[mt][nt] = MFMA16(af[mt], bfr[nt], acc[mt][nt]);
    }

    if (mat == 1) {
        // m = x-row (s), n = feature. Regs = 4 consecutive s at fixed dh.
        #pragma unroll
        for (int nt = 0; nt < 4; ++nt) {
            int col = nloc0 + nw + nt * 16 + c;
            int h = col >> 6, dh = col & 63;
            float bias = bsel[col];
            #pragma unroll
            for (int mt = 0; mt < 4; ++mt) {
                int xr0 = row0 + mw + mt * 16 + quad * 4;
                int bl = xr0 >> 11, s0 = xr0 & 2047;
                ushort4 o = pack4(acc[mt][nt][0] + bias, acc[mt][nt][1] + bias,
                                  acc[mt][nt][2] + bias, acc[mt][nt][3] + bias);
                *(ushort4*)&vt[((size_t)(bl * HH + h) * DHH + dh) * SS + s0] = o;
            }
        }
    } else {
        unsigned short* dst = (mat == 0) ? qm : km;
        // log2(e)/sqrt(512) for Q (exp2-domain softmax), 1.0 for K
        const float qscale = (mat == 0) ? 0.06375871448932861f : 1.0f;
        // m = feature (dh), n = x-row (s). Regs = 4 consecutive dh.
        #pragma unroll
        for (int mt = 0; mt < 4; ++mt) {
            int col0 = nloc0 + mw + mt * 16 + quad * 4;   // 4-aligned
            int h = col0 >> 6, dh0 = col0 & 63;
            int f0 = dh0 >> 1;                            // even
            float4 bias4 = *(const float4*)&bsel[col0];
            #pragma unroll
            for (int nt = 0; nt < 4; ++nt) {
                int xr = row0 + nw + nt * 16 + c;
                int bl = xr >> 11, s = xr & 2047;
                float2 cs = *(const float2*)&cos_t[s * 32 + f0];
                float2 sn = *(const float2*)&sin_t[s * 32 + f0];
                float c0 = cs.x * qscale, s0v = sn.x * qscale;
                float c1 = cs.y * qscale, s1v = sn.y * qscale;
                float v0 = acc[mt][nt][0] + bias4.x;
                float v1 = acc[mt][nt][1] + bias4.y;
                float v2 = acc[mt][nt][2] + bias4.z;
                float v3 = acc[mt][nt][3] + bias4.w;
                ushort4 o = pack4(v0 * c0 - v1 * s0v, v1 * c0 + v0 * s0v,
                                  v2 * c1 - v3 * s1v, v3 * c1 + v2 * s1v);
                *(ushort4*)&dst[((size_t)(bl * HH + h) * SS + s) * DHH + dh0] = o;
            }
        }
    }
}

// ---------------------------------------------------------------
// K2: causal flash attention, bf16 MFMA, PAIRED q-tiles for perfect
// load balance. Br=64 (4 waves x 16 q); block processes q-tile
// (31 - pair) then (pair): every block = exactly 33 key-tiles.
// Double-buffered K/V via async global_load_lds (XOR-swizzled),
// PIPELINE_SYNC per tile. S^T = K Q^T -> packed exp2 -> b64 LDS;
// O^T = V^T P^T; l via ones-row MFMA; no max-sub (scores bounded).
// Epilogue: O^T -> LDS -> 128B-coalesced bf16 stores.
// ---------------------------------------------------------------
#define S_P 72

__global__ __launch_bounds__(256, 2) void attn_mfma_kernel(
    const unsigned short* __restrict__ qm,
    const unsigned short* __restrict__ km,
    const unsigned short* __restrict__ vt,
    unsigned short* __restrict__ inter)
{
    __shared__ __align__(16) unsigned short Ks[2][4096];   // [key][dh], swizzled
    __shared__ __align__(16) unsigned short Vs[2][4096];   // [dh][key], swizzled
    __shared__ __align__(16) unsigned short Ps[64 * S_P];  // P^T / O staging

    const int tid  = threadIdx.x;
    const int w    = tid >> 6;
    const int lane = tid & 63;
    const int c    = lane & 15;
    const int quad = lane >> 4;

    const int pair = blockIdx.x;        // 0..15
    const int blh  = blockIdx.y;        // 0..31
    const int h    = blh & 7;
    const int bl   = blh >> 3;

    const size_t seq_base = (size_t)blh * SS * DHH;  // qm, km
    const size_t vt_base  = (size_t)blh * DHH * SS;  // vt [dh][s]

    bf16x8 ones;
    #pragma unroll
    for (int i = 0; i < 8; ++i) ones[i] = (short)0x3F80;   // bf16 1.0

    auto stage = [&](int kt, int b) {
        const unsigned short* kg = km + seq_base + (size_t)(kt * 64) * DHH;
        const unsigned short* vg = vt + vt_base + kt * 64;
        #pragma unroll
        for (int it = 0; it < 2; ++it) {
            int L   = it * 256 + tid;        // 0..511
            int row = L >> 3;
            int gch = (L & 7) ^ (row & 7);
            gload16(kg + row * DHH + gch * 8, &Ks[b][L * 8]);
            gload16(vg + (size_t)row * SS + gch * 8, &Vs[b][L * 8]);
        }
    };

    for (int leg = 0; leg < 2; ++leg) {
        const int qt     = leg ? pair : (31 - pair);
        const int ntiles = qt + 1;
        const int qw     = qt * 64 + w * 16;   // this wave's 16-query strip

        // Q fragments (B-operand), 16 q x 64 dh
        bf16x8 qf[2];
        #pragma unroll
        for (int kk = 0; kk < 2; ++kk)
            qf[kk] = *(const bf16x8*)(qm + seq_base +
                (size_t)(qw + c) * DHH + kk * 32 + quad * 8);

        f32x4 oacc[4];   // [dh-tile], O^T layout (64 dh x 16 q)
        f32x4 lacc;
        #pragma unroll
        for (int i = 0; i < 4; ++i)
            #pragma unroll
            for (int r = 0; r < 4; ++r) oacc[i][r] = 0.f;
        #pragma unroll
        for (int r = 0; r < 4; ++r) lacc[r] = 0.f;

        stage(0, 0);

        for (int kt = 0; kt < ntiles; ++kt) {
            const int b = kt & 1;
            PIPELINE_SYNC();                 // tile kt staged; kt-1 compute done
            if (kt + 1 < ntiles) stage(kt + 1, b ^ 1);   // flies under compute

            // ---- S^T = K Q^T : [64 key][16 q] = 4x1 tiles
            f32x4 sacc[4];
            #pragma unroll
            for (int mt = 0; mt < 4; ++mt)
                #pragma unroll
                for (int r = 0; r < 4; ++r) sacc[mt][r] = 0.f;
            #pragma unroll
            for (int kk = 0; kk < 2; ++kk) {
                bf16x8 kf[4];
                #pragma unroll
                for (int mt = 0; mt < 4; ++mt) {
                    int rr = mt * 16 + c;
                    kf[mt] = *(const bf16x8*)&Ks[b][rr * 64 +
                        (((kk * 4 + quad) ^ (rr & 7)) * 8)];
                }
                #pragma unroll
                for (int mt = 0; mt < 4; ++mt)
                    sacc[mt] = MFMA16(kf[mt], qf[kk], sacc[mt]);
            }

            // ---- P^T = exp2(S^T), mask only on the diagonal tile
            const bool need_mask = (kt == qt);
            const int q = qw + c;
            #pragma unroll
            for (int mt = 0; mt < 4; ++mt) {
                unsigned u[4];
                #pragma unroll
                for (int r = 0; r < 4; ++r) {
                    float p = EXP2F(sacc[mt][r]);
                    if (need_mask) {
                        int key = kt * 64 + mt * 16 + quad * 4 + r;
                        if (key > q) p = 0.f;
                    }
                    u[r] = bcast(p) + 0x8000u;   // round-half-up to bf16
                }
                uint2 d;
                d.x = __builtin_amdgcn_perm(u[1], u[0], 0x07060302u);
                d.y = __builtin_amdgcn_perm(u[3], u[2], 0x07060302u);
                *(uint2*)&Ps[(w * 16 + c) * S_P + mt * 16 + quad * 4] = d;
            }

            // ---- O^T += V^T P^T ; l += ones * P^T  (Ps rows wave-private)
            #pragma unroll
            for (int kk = 0; kk < 2; ++kk) {
                bf16x8 bp = *(const bf16x8*)&Ps[(w * 16 + c) * S_P +
                                                kk * 32 + quad * 8];
                lacc = MFMA16(ones, bp, lacc);
                #pragma unroll
                for (int mt4 = 0; mt4 < 4; ++mt4) {
                    int rv = mt4 * 16 + c;
                    bf16x8 av = *(const bf16x8*)&Vs[b][rv * 64 +
                        (((kk * 4 + quad) ^ (rv & 7)) * 8)];
                    oacc[mt4] = MFMA16(av, bp, oacc[mt4]);
                }
            }
        }

        // ---- Epilogue: normalize, O^T -> LDS, coalesced bf16 stores
        float il = 1.f / lacc[0];
        #pragma unroll
        for (int mt4 = 0; mt4 < 4; ++mt4) {
            ushort4 o = pack4(oacc[mt4][0] * il, oacc[mt4][1] * il,
                              oacc[mt4][2] * il, oacc[mt4][3] * il);
            *(ushort4*)&Ps[(w * 16 + c) * S_P + mt4 * 16 + quad * 4] = o;
        }
        __syncthreads();   // all waves' O rows visible
        #pragma unroll
        for (int pass = 0; pass < 2; ++pass) {
            int idx  = pass * 256 + tid;   // 0..511
            int srow = idx >> 3;           // 0..63 (q-local)
            int chnk = idx & 7;            // 16B chunk within 128B row
            bf16x8 v = *(const bf16x8*)&Ps[srow * S_P + chnk * 8];
            *(bf16x8*)&inter[((size_t)bl * SS + qt * 64 + srow) * DD +
                             h * DHH + chnk * 8] = v;
        }
        __syncthreads();   // readers done before next leg reuses Ps
    }
}

// ---------------------------------------------------------------
// K3: output projection, bf16 MFMA, swapped orientation (A=Wo,
// B=inter) so lane regs = 4 consecutive out-features -> float4
// stores. Tile 64 features x 128 rows, dbuf, pipelined sync.
// ---------------------------------------------------------------
__global__ __launch_bounds__(256) void outproj_mfma_kernel(
    const unsigned short* __restrict__ ib,
    const unsigned short* __restrict__ wob,
    const float* __restrict__ bo, float* __restrict__ out)
{
    __shared__ __align__(16) unsigned short As[2][2048];   //  64 wo-rows x 32
    __shared__ __align__(16) unsigned short Bs[2][4096];   // 128 x-rows  x 32

    const int tid  = threadIdx.x;
    const int w    = tid >> 6;
    const int lane = tid & 63;
    const int c    = lane & 15;
    const int quad = lane >> 4;
    const int mw   = (w & 1) * 32;    // feature half
    const int nw   = (w >> 1) * 64;   // row half

    const int n0   = blockIdx.x * 64;    // feature tile
    const int row0 = blockIdx.y * 128;   // row tile

    const unsigned short* aSrc = wob + (size_t)n0   * DD;
    const unsigned short* bSrc = ib  + (size_t)row0 * DD;

    auto stage = [&](int k0, int bb) {
        int L = tid;                          // 0..255 -> 64 rows
        gload16(aSrc + (size_t)(L >> 2) * DD + k0 + (L & 3) * 8,
                &As[bb][L * 8]);
        #pragma unroll
        for (int it = 0; it < 2; ++it) {
            int L2 = it * 256 + tid;          // 0..511 -> 128 rows
            gload16(bSrc + (size_t)(L2 >> 2) * DD + k0 + (L2 & 3) * 8,
                    &Bs[bb][L2 * 8]);
        }
    };

    f32x4 acc[2][4];
    #pragma unroll
    for (int i = 0; i < 2; ++i)
        #pragma unroll
        for (int j = 0; j < 4; ++j)
            #pragma unroll
            for (int r = 0; r < 4; ++r) acc[i][j][r] = 0.f;

    stage(0, 0);

    for (int k0 = 0; k0 < DD; k0 += 32) {
        const int bb = (k0 >> 5) & 1;
        PIPELINE_SYNC();
        if (k0 + 32 < DD) stage(k0 + 32, bb ^ 1);

        bf16x8 af[2], bfr[4];
        #pragma unroll
        for (int mt = 0; mt < 2; ++mt)
            af[mt] = *(const bf16x8*)&As[bb][(mw + mt * 16 + c) * 32 + quad * 8];
        #pragma unroll
        for (int nt = 0; nt < 4; ++nt)
            bfr[nt] = *(const bf16x8*)&Bs[bb][(nw + nt * 16 + c) * 32 + quad * 8];
        #pragma unroll
        for (int mt = 0; mt < 2; ++mt)
            #pragma unroll
            for (int nt = 0; nt < 4; ++nt)
                acc[mt][nt] = MFMA16(af[mt], bfr[nt], acc[mt][nt]);
    }

    #pragma unroll
    for (int mt = 0; mt < 2; ++mt) {
        int col0 = n0 + mw + mt * 16 + quad * 4;   // 4-aligned
        float4 b4 = *(const float4*)&bo[col0];
        #pragma unroll
        for (int nt = 0; nt < 4; ++nt) {
            int xr = row0 + nw + nt * 16 + c;
            float4 o;
            o.x = acc[mt][nt][0] + b4.x;
            o.y = acc[mt][nt][1] + b4.y;
            o.z = acc[mt][nt][2] + b4.z;
            o.w = acc[mt][nt][3] + b4.w;
            *(float4*)&out[(size_t)xr * DD + col0] = o;
        }
    }
}

// ---------------------------------------------------------------
extern "C" void kernel_launch(void* const* d_in, const int* in_sizes, int n_in,
                              void* d_out, int out_size, void* d_ws, size_t ws_size,
                              hipStream_t stream)
{
    const float* x  = (const float*)d_in[0];
    const float* Wq = (const float*)d_in[1];
    const float* bq = (const float*)d_in[2];
    const float* Wk = (const float*)d_in[3];
    const float* bk = (const float*)d_in[4];
    const float* Wv = (const float*)d_in[5];
    const float* bv = (const float*)d_in[6];
    const float* Wo = (const float*)d_in[7];
    const float* bo = (const float*)d_in[8];
    float* out = (float*)d_out;
    char* ws = (char*)d_ws;

    // Workspace layout (bytes):
    unsigned short* inter = (unsigned short*)(ws);             //  8,388,608
    float* cos_t = (float*)(ws + 8388608);                     //    262,144
    float* sin_t = (float*)(ws + 8650752);                     //    262,144
    unsigned short* xb  = (unsigned short*)(ws + 8912896);     //  8,388,608
    unsigned short* wqb = (unsigned short*)(ws + 17301504);    //    524,288
    unsigned short* wkb = (unsigned short*)(ws + 17825792);    //    524,288
    unsigned short* wvb = (unsigned short*)(ws + 18350080);    //    524,288
    unsigned short* wob = (unsigned short*)(ws + 18874368);    //    524,288
    unsigned short* qm  = (unsigned short*)(ws + 19398656);    //  8,388,608
    unsigned short* km  = (unsigned short*)(ws + 27787264);    //  8,388,608
    unsigned short* vt  = (unsigned short*)(ws + 36175872);    //  8,388,608
    // total 44,564,480 bytes

    prep_kernel<<<dim3(5376), dim3(256), 0, stream>>>(
        x, Wq, Wk, Wv, Wo, xb, cos_t, sin_t);
    qkv_mfma_kernel<<<dim3(12, 64), dim3(256), 0, stream>>>(
        xb, wqb, wkb, wvb, bq, bk, bv, cos_t, sin_t, qm, km, vt);
    attn_mfma_kernel<<<dim3(16, 32), dim3(256), 0, stream>>>(qm, km, vt, inter);
    outproj_mfma_kernel<<<dim3(8, 64), dim3(256), 0, stream>>>(inter, wob, bo, out);
}